// Round 1
// baseline (883.955 us; speedup 1.0000x reference)
//
#include <hip/hip_runtime.h>
#include <math.h>

#define N_TOT 2048
#define NE    1024
#define NA    3
#define BATCH 512
#define IN_SZ 512
#define SS    10240   // STATE_SIZE
#define AI_OFF 3072
#define BE_OFF 6144
#define BI_OFF 7168
#define X_OFF  8192

// ---------- device helpers ----------

__device__ __forceinline__ float sp_f(float x) {
    // softplus, stable: max(x,0) + log1p(exp(-|x|))  (== jnp.logaddexp(x,0))
    return fmaxf(x, 0.f) + log1pf(expf(-fabsf(x)));
}

__device__ __forceinline__ float psig(float x) {
    // piecewise_sigmoid with S_a=0.9, S_c=0: a=0.45, k=5
    // x <  -0.55 -> 0
    // -0.55 <= x < -0.45 -> 5*(x+0.55)^2
    // -0.45 <= x <= 0.45 -> x+0.5
    // 0.45 < x <= 0.55 -> 1 - 5*(x-0.55)^2
    // x > 0.55 -> 1
    if (x >= -0.45f) {
        if (x <= 0.45f) return x + 0.5f;
        if (x > 0.55f)  return 1.f;
        float d = x - 0.55f;
        return 1.f - 5.f * d * d;
    }
    if (x < -0.55f) return 0.f;
    float d = x + 0.55f;
    return 5.f * d * d;
}

// ---------- params kernel ----------
// P layout: 0 g_x | 1..3 g_aE | 4..6 g_aI | 7..9 c_E | 10..12 c_I
//           13..15 c0_E | 16..18 c0_I | 19 kb_rec_E | 20 kb_rel_E | 21 kb_rec_I | 22 kb_rel_I
__global__ void k_params(const float* ltd, const float* loE, const float* hiE,
                         const float* lcE, const float* c0E,
                         const float* loI, const float* hiI,
                         const float* lcI, const float* c0I,
                         const float* recE, const float* relE,
                         const float* recI, const float* relI,
                         float* __restrict__ P) {
    if (threadIdx.x == 0 && blockIdx.x == 0) {
        const float DTf = (float)(0.04 / 6.0);
        P[0] = DTf / sp_f(ltd[0]);
        float sElo = sp_f(loE[0]), sEhi = sp_f(hiE[0]);
        float sIlo = sp_f(loI[0]), sIhi = sp_f(hiI[0]);
        for (int j = 0; j < 3; ++j) {
            float t = 0.5f * (float)j;
            float tauE = sElo + (sEhi - sElo) * t;
            float tauI = sIlo + (sIhi - sIlo) * t;
            P[1 + j]  = DTf / tauE;
            P[4 + j]  = DTf / tauI;
            P[7 + j]  = sp_f(lcE[j]);
            P[10 + j] = sp_f(lcI[j]);
            P[13 + j] = c0E[j];
            P[16 + j] = c0I[j];
        }
        P[19] = DTf / sp_f(recE[0]);
        P[20] = DTf / sp_f(relE[0]);
        P[21] = DTf / sp_f(recI[0]);
        P[22] = DTf / sp_f(relI[0]);
    }
}

// ---------- W_eff = softplus(W_raw) * sign(col) * mask ----------
__global__ __launch_bounds__(256) void k_weff(const float* __restrict__ Wr,
                                              const float* __restrict__ mask,
                                              float* __restrict__ We) {
    int i = blockIdx.x * 256 + threadIdx.x;   // float4 index; 1M total
    float4 w = ((const float4*)Wr)[i];
    float4 m = ((const float4*)mask)[i];
    int col = (i * 4) & (N_TOT - 1);
    float s = (col < NE) ? 1.f : -1.f;
    float4 o;
    o.x = sp_f(w.x) * m.x * s;
    o.y = sp_f(w.y) * m.y * s;
    o.z = sp_f(w.z) * m.z * s;
    o.w = sp_f(w.w) * m.w * s;
    ((float4*)We)[i] = o;
}

// ---------- first r / r_dep from initial state ----------
__global__ __launch_bounds__(256) void k_r_first(const float* __restrict__ st,
                                                 const float* __restrict__ P,
                                                 float* __restrict__ r_ws,
                                                 float* __restrict__ rdep) {
    int idx = blockIdx.x * 256 + threadIdx.x;     // b*N + n
    int m = idx >> 11, n = idx & (N_TOT - 1);
    const float* row = st + (size_t)m * SS;
    bool isE = n < NE;
    int na = isE ? n : n - NE;
    const float* a = row + (isE ? 0 : AI_OFF) + 3 * na;
    const float* c = P + (isE ? 7 : 10);
    float x = row[X_OFF + n];
    float xeff = x - (a[0] * c[0] + a[1] * c[1] + a[2] * c[2]);
    float r = psig(xeff);
    float bb = row[isE ? (BE_OFF + n) : (BI_OFF + na)];
    r_ws[idx] = r;
    rdep[idx] = bb * r;
}

// ---------- tiled NT GEMM:  C[m][n] = sum_k A[m][k]*Bt[n][k]  ----------
// EPI 0: outIext[m*N+n] = acc + a0[n]
// EPI 1: full fused state update (x, a, b; optionally next r/r_dep)
#define BM 64
#define BN 64
#define BK 16

template<int EPI, bool CALC_R>
__global__ __launch_bounds__(256)
void gemm_nt(const float* __restrict__ A, const float* __restrict__ Bt, int K,
             const float* __restrict__ a0,
             const float* __restrict__ Iext,
             float* __restrict__ outIext,
             float* __restrict__ stateOut,
             const float* __restrict__ P,
             float* __restrict__ r_ws,
             float* __restrict__ rdep_out) {
    __shared__ __align__(16) float As[BK][BM + 4];
    __shared__ __align__(16) float Bs[BK][BN + 4];
    const int tid = threadIdx.x;
    const int bn = blockIdx.x * BN;
    const int bm = blockIdx.y * BM;
    const int tx = tid & 15, ty = tid >> 4;
    const int lr = tid >> 2;
    const int lk = (tid & 3) << 2;
    const float* Ap = A + (size_t)(bm + lr) * K + lk;
    const float* Bp = Bt + (size_t)(bn + lr) * K + lk;
    float acc[4][4] = {};
    for (int k0 = 0; k0 < K; k0 += BK) {
        float4 av = *(const float4*)(Ap + k0);
        float4 bv = *(const float4*)(Bp + k0);
        As[lk + 0][lr] = av.x; As[lk + 1][lr] = av.y;
        As[lk + 2][lr] = av.z; As[lk + 3][lr] = av.w;
        Bs[lk + 0][lr] = bv.x; Bs[lk + 1][lr] = bv.y;
        Bs[lk + 2][lr] = bv.z; Bs[lk + 3][lr] = bv.w;
        __syncthreads();
#pragma unroll
        for (int kk = 0; kk < BK; ++kk) {
            const float4 a4 = *(const float4*)&As[kk][ty << 2];
            const float4 b4 = *(const float4*)&Bs[kk][tx << 2];
            const float ar[4] = {a4.x, a4.y, a4.z, a4.w};
            const float br[4] = {b4.x, b4.y, b4.z, b4.w};
#pragma unroll
            for (int i = 0; i < 4; ++i)
#pragma unroll
                for (int j = 0; j < 4; ++j)
                    acc[i][j] = fmaf(ar[i], br[j], acc[i][j]);
        }
        __syncthreads();
    }

    if (EPI == 0) {
#pragma unroll
        for (int i = 0; i < 4; ++i) {
            int m = bm + (ty << 2) + i;
#pragma unroll
            for (int j = 0; j < 4; ++j) {
                int n = bn + (tx << 2) + j;
                outIext[m * N_TOT + n] = acc[i][j] + a0[n];
            }
        }
    } else {
        const float gx = P[0];
        const float inv1gx = 1.f / (1.f + gx);
#pragma unroll
        for (int i = 0; i < 4; ++i) {
            int m = bm + (ty << 2) + i;
            float* row = stateOut + (size_t)m * SS;
#pragma unroll
            for (int j = 0; j < 4; ++j) {
                int n = bn + (tx << 2) + j;
                int idx = m * N_TOT + n;
                float Isyn = acc[i][j] + Iext[idx];
                float x = row[X_OFF + n];
                float xn = (x + gx * Isyn) * inv1gx;
                row[X_OFF + n] = xn;

                float r = r_ws[idx];
                bool isE = n < NE;
                int na = isE ? n : n - NE;
                float* a = row + (isE ? 0 : AI_OFF) + 3 * na;
                const float* ga = P + (isE ? 1 : 4);
                const float* c0 = P + (isE ? 13 : 16);
                float av0 = (a[0] + ga[0] * (r + c0[0])) / (1.f + ga[0]);
                float av1 = (a[1] + ga[1] * (r + c0[1])) / (1.f + ga[1]);
                float av2 = (a[2] + ga[2] * (r + c0[2])) / (1.f + ga[2]);
                a[0] = av0; a[1] = av1; a[2] = av2;

                float kbrec = isE ? P[19] : P[21];
                float kbrel = isE ? P[20] : P[22];
                int boff = isE ? (BE_OFF + n) : (BI_OFF + na);
                float bb = row[boff];
                bb = (bb + kbrec) / (1.f + kbrec + kbrel * r);
                row[boff] = bb;

                if (CALC_R) {
                    const float* c = P + (isE ? 7 : 10);
                    float xeff = xn - (av0 * c[0] + av1 * c[1] + av2 * c[2]);
                    float rn = psig(xeff);
                    r_ws[idx] = rn;
                    rdep_out[idx] = bb * rn;
                }
            }
        }
    }
}

// ---------- launch ----------
extern "C" void kernel_launch(void* const* d_in, const int* in_sizes, int n_in,
                              void* d_out, int out_size, void* d_ws, size_t ws_size,
                              hipStream_t stream) {
    const float* W_raw = (const float*)d_in[0];
    const float* W_in  = (const float*)d_in[1];
    const float* mask  = (const float*)d_in[2];
    const float* a_0   = (const float*)d_in[3];
    const float* ltd   = (const float*)d_in[4];
    const float* loE   = (const float*)d_in[5];
    const float* hiE   = (const float*)d_in[6];
    const float* lcE   = (const float*)d_in[7];
    const float* c0E   = (const float*)d_in[8];
    const float* loI   = (const float*)d_in[9];
    const float* hiI   = (const float*)d_in[10];
    const float* lcI   = (const float*)d_in[11];
    const float* c0I   = (const float*)d_in[12];
    const float* recE  = (const float*)d_in[13];
    const float* relE  = (const float*)d_in[14];
    const float* recI  = (const float*)d_in[15];
    const float* relI  = (const float*)d_in[16];
    const float* u     = (const float*)d_in[17];
    const float* state = (const float*)d_in[18];
    float* out = (float*)d_out;
    float* ws  = (float*)d_ws;

    float* We    = ws;                                   // 4M floats (16MB)
    float* Iext  = We + (size_t)N_TOT * N_TOT;           // 1M
    float* r_ws  = Iext + (size_t)BATCH * N_TOT;         // 1M
    float* rdep0 = r_ws + (size_t)BATCH * N_TOT;         // 1M
    float* rdep1 = rdep0 + (size_t)BATCH * N_TOT;        // 1M
    float* P     = rdep1 + (size_t)BATCH * N_TOT;        // 32

    // working state lives in d_out (same layout as input state)
    hipMemcpyAsync(out, state, (size_t)BATCH * SS * sizeof(float),
                   hipMemcpyDeviceToDevice, stream);

    k_params<<<1, 64, 0, stream>>>(ltd, loE, hiE, lcE, c0E, loI, hiI, lcI, c0I,
                                   recE, relE, recI, relI, P);

    k_weff<<<(N_TOT * N_TOT / 4) / 256, 256, 0, stream>>>(W_raw, mask, We);

    // I_ext = u @ W_in^T + a_0
    gemm_nt<0, false><<<dim3(N_TOT / BN, BATCH / BM), 256, 0, stream>>>(
        u, W_in, IN_SZ, a_0, nullptr, Iext, nullptr, nullptr, nullptr, nullptr);

    k_r_first<<<(BATCH * N_TOT) / 256, 256, 0, stream>>>(out, P, r_ws, rdep0);

    float* rbufs[2] = {rdep0, rdep1};
    for (int t = 0; t < 6; ++t) {
        float* rin  = rbufs[t & 1];
        float* rout = rbufs[(t + 1) & 1];
        if (t < 5)
            gemm_nt<1, true><<<dim3(N_TOT / BN, BATCH / BM), 256, 0, stream>>>(
                rin, We, N_TOT, nullptr, Iext, nullptr, out, P, r_ws, rout);
        else
            gemm_nt<1, false><<<dim3(N_TOT / BN, BATCH / BM), 256, 0, stream>>>(
                rin, We, N_TOT, nullptr, Iext, nullptr, out, P, r_ws, nullptr);
    }
}

// Round 3
// 374.910 us; speedup vs baseline: 2.3578x; 2.3578x over previous
//
#include <hip/hip_runtime.h>
#include <math.h>

#define N_TOT 2048
#define NE    1024
#define BATCH 512
#define IN_SZ 512
#define SS    10240   // STATE_SIZE
#define AI_OFF 3072
#define BE_OFF 6144
#define BI_OFF 7168
#define X_OFF  8192

typedef __attribute__((ext_vector_type(8))) short bf16x8;
typedef __attribute__((ext_vector_type(4))) float f32x4;

// ---------- device helpers ----------

__device__ __forceinline__ float sp_f(float x) {
    return fmaxf(x, 0.f) + log1pf(expf(-fabsf(x)));
}

__device__ __forceinline__ float psig(float x) {
    if (x >= -0.45f) {
        if (x <= 0.45f) return x + 0.5f;
        if (x > 0.55f)  return 1.f;
        float d = x - 0.55f;
        return 1.f - 5.f * d * d;
    }
    if (x < -0.55f) return 0.f;
    float d = x + 0.55f;
    return 5.f * d * d;
}

__device__ __forceinline__ ushort f2bf(float f) {
    unsigned u = __float_as_uint(f);
    unsigned r = (u + 0x7fffu + ((u >> 16) & 1u)) >> 16;
    return (ushort)r;
}

__device__ __forceinline__ void gload16(const void* g, void* l) {
    __builtin_amdgcn_global_load_lds(
        (const __attribute__((address_space(1))) void*)g,
        (__attribute__((address_space(3))) void*)l, 16, 0, 0);
}

// ---------- params ----------
// P: 0 g_x | 1..3 g_aE | 4..6 g_aI | 7..9 c_E | 10..12 c_I | 13..15 c0_E
//    16..18 c0_I | 19 kb_rec_E | 20 kb_rel_E | 21 kb_rec_I | 22 kb_rel_I
//    23..25 1/(1+g_aE) | 26..28 1/(1+g_aI) | 29 1/(1+g_x)
__global__ void k_params(const float* ltd, const float* loE, const float* hiE,
                         const float* lcE, const float* c0E,
                         const float* loI, const float* hiI,
                         const float* lcI, const float* c0I,
                         const float* recE, const float* relE,
                         const float* recI, const float* relI,
                         float* __restrict__ P) {
    if (threadIdx.x == 0 && blockIdx.x == 0) {
        const float DTf = (float)(0.04 / 6.0);
        float gx = DTf / sp_f(ltd[0]);
        P[0] = gx;
        P[29] = 1.f / (1.f + gx);
        float sElo = sp_f(loE[0]), sEhi = sp_f(hiE[0]);
        float sIlo = sp_f(loI[0]), sIhi = sp_f(hiI[0]);
        for (int j = 0; j < 3; ++j) {
            float t = 0.5f * (float)j;
            float gE = DTf / (sElo + (sEhi - sElo) * t);
            float gI = DTf / (sIlo + (sIhi - sIlo) * t);
            P[1 + j] = gE;  P[23 + j] = 1.f / (1.f + gE);
            P[4 + j] = gI;  P[26 + j] = 1.f / (1.f + gI);
            P[7 + j]  = sp_f(lcE[j]);
            P[10 + j] = sp_f(lcI[j]);
            P[13 + j] = c0E[j];
            P[16 + j] = c0I[j];
        }
        P[19] = DTf / sp_f(recE[0]);
        P[20] = DTf / sp_f(relE[0]);
        P[21] = DTf / sp_f(recI[0]);
        P[22] = DTf / sp_f(relI[0]);
    }
}

// ---------- W_eff (bf16) = softplus(W_raw) * sign(col) * mask ----------
__global__ __launch_bounds__(256) void k_weff(const float* __restrict__ Wr,
                                              const float* __restrict__ mask,
                                              ushort* __restrict__ We) {
    int i = blockIdx.x * 256 + threadIdx.x;   // float4 index; 1M total
    float4 w = ((const float4*)Wr)[i];
    float4 m = ((const float4*)mask)[i];
    int col = (i * 4) & (N_TOT - 1);
    float s = (col < NE) ? 1.f : -1.f;
    ushort4 o;
    o.x = f2bf(sp_f(w.x) * m.x * s);
    o.y = f2bf(sp_f(w.y) * m.y * s);
    o.z = f2bf(sp_f(w.z) * m.z * s);
    o.w = f2bf(sp_f(w.w) * m.w * s);
    ((ushort4*)We)[i] = o;
}

// ---------- fp32 -> bf16 bulk convert ----------
__global__ __launch_bounds__(256) void k_cvt(const float* __restrict__ in,
                                             ushort* __restrict__ out) {
    int i = blockIdx.x * 256 + threadIdx.x;   // float4 index
    float4 v = ((const float4*)in)[i];
    ushort4 o;
    o.x = f2bf(v.x); o.y = f2bf(v.y); o.z = f2bf(v.z); o.w = f2bf(v.w);
    ((ushort4*)out)[i] = o;
}

// ---------- first r / r_dep ----------
__global__ __launch_bounds__(256) void k_r_first(const float* __restrict__ st,
                                                 const float* __restrict__ P,
                                                 float* __restrict__ r_ws,
                                                 ushort* __restrict__ rdep) {
    int idx = blockIdx.x * 256 + threadIdx.x;     // b*N + n
    int m = idx >> 11, n = idx & (N_TOT - 1);
    const float* row = st + (size_t)m * SS;
    bool isE = n < NE;
    int na = isE ? n : n - NE;
    const float* a = row + (isE ? 0 : AI_OFF) + 3 * na;
    const float* c = P + (isE ? 7 : 10);
    float x = row[X_OFF + n];
    float xeff = x - (a[0] * c[0] + a[1] * c[1] + a[2] * c[2]);
    float r = psig(xeff);
    float bb = row[isE ? (BE_OFF + n) : (BI_OFF + na)];
    r_ws[idx] = r;
    rdep[idx] = f2bf(bb * r);
}

// ---------- MFMA NT GEMM: C[m][n] = sum_k A[m][k]*Bt[n][k] ----------
// 64x64 tile, 4 waves (2x2), each wave 32x32 via 2x2 frags of 16x16x32.
// EPI 0: outIext = acc + a0[n];  EPI 1: fused state update.
template<int EPI, bool CALC_R>
__global__ __launch_bounds__(256)
void mgemm(const ushort* __restrict__ A, const ushort* __restrict__ Bt, int K,
           const float* __restrict__ a0,
           const float* __restrict__ Iext,
           float* __restrict__ outIext,
           float* __restrict__ stateOut,
           const float* __restrict__ P,
           float* __restrict__ r_ws,
           ushort* __restrict__ rdep_out) {
    __shared__ __align__(16) ushort lds[2][2][64 * 32];   // [buf][A/B][row*32+k]
    const int tid = threadIdx.x;
    const int bm = blockIdx.y * 64;
    const int bn = blockIdx.x * 64;
    const int wv = tid >> 6;
    const int lane = tid & 63;
    const int wr = wv >> 1, wc = wv & 1;

    // staging: thread -> LDS row (tid>>2), 16B chunk (tid&3); global source
    // pre-swizzled so linear LDS holds chunk' = chunk ^ ((row>>1)&3)
    const int srow = tid >> 2;
    const int sc = tid & 3;
    const int gk = (sc ^ ((srow >> 1) & 3)) * 8;
    const ushort* gA = A + (size_t)(bm + srow) * K + gk;
    const ushort* gB = Bt + (size_t)(bn + srow) * K + gk;

    // fragment ds_read byte offsets within a tile (k0-invariant)
    int aoff[2], boff[2];
    {
        const int kc = lane >> 4;
        const int rr = lane & 15;
#pragma unroll
        for (int i = 0; i < 2; ++i) {
            int r = wr * 32 + i * 16 + rr;
            aoff[i] = r * 64 + ((kc ^ ((r >> 1) & 3)) << 4);
        }
#pragma unroll
        for (int j = 0; j < 2; ++j) {
            int r = wc * 32 + j * 16 + rr;
            boff[j] = r * 64 + ((kc ^ ((r >> 1) & 3)) << 4);
        }
    }

    f32x4 acc[2][2];
#pragma unroll
    for (int i = 0; i < 2; ++i)
#pragma unroll
        for (int j = 0; j < 2; ++j)
            acc[i][j] = f32x4{0.f, 0.f, 0.f, 0.f};

    // prologue stage into buf 0
    gload16(gA, (char*)&lds[0][0][0] + wv * 1024);
    gload16(gB, (char*)&lds[0][1][0] + wv * 1024);
    __syncthreads();

    const int nsteps = K >> 5;
    int cur = 0;
    for (int s = 0; s < nsteps; ++s) {
        if (s + 1 < nsteps) {
            gload16(gA + (s + 1) * 32, (char*)&lds[cur ^ 1][0][0] + wv * 1024);
            gload16(gB + (s + 1) * 32, (char*)&lds[cur ^ 1][1][0] + wv * 1024);
        }
        const char* At = (const char*)&lds[cur][0][0];
        const char* Bl = (const char*)&lds[cur][1][0];
        bf16x8 af0 = *(const bf16x8*)(At + aoff[0]);
        bf16x8 af1 = *(const bf16x8*)(At + aoff[1]);
        bf16x8 bg0 = *(const bf16x8*)(Bl + boff[0]);
        bf16x8 bg1 = *(const bf16x8*)(Bl + boff[1]);
        acc[0][0] = __builtin_amdgcn_mfma_f32_16x16x32_bf16(af0, bg0, acc[0][0], 0, 0, 0);
        acc[0][1] = __builtin_amdgcn_mfma_f32_16x16x32_bf16(af0, bg1, acc[0][1], 0, 0, 0);
        acc[1][0] = __builtin_amdgcn_mfma_f32_16x16x32_bf16(af1, bg0, acc[1][0], 0, 0, 0);
        acc[1][1] = __builtin_amdgcn_mfma_f32_16x16x32_bf16(af1, bg1, acc[1][1], 0, 0, 0);
        __syncthreads();
        cur ^= 1;
    }

    // epilogue; C layout: col = lane&15, row = (lane>>4)*4 + reg   [m89]
    if (EPI == 0) {
#pragma unroll
        for (int i = 0; i < 2; ++i) {
#pragma unroll
            for (int j = 0; j < 2; ++j) {
                int m0 = bm + wr * 32 + i * 16 + (lane >> 4) * 4;
                int n = bn + wc * 32 + j * 16 + (lane & 15);
                float av = a0[n];
#pragma unroll
                for (int q = 0; q < 4; ++q)
                    outIext[(m0 + q) * N_TOT + n] = acc[i][j][q] + av;
            }
        }
    } else {
        const float gx = P[0];
        const float inv1gx = P[29];
#pragma unroll
        for (int i = 0; i < 2; ++i) {
#pragma unroll
            for (int j = 0; j < 2; ++j) {
                int m0 = bm + wr * 32 + i * 16 + (lane >> 4) * 4;
                int n = bn + wc * 32 + j * 16 + (lane & 15);
                bool isE = n < NE;
                int na = isE ? n : n - NE;
                const float* ga = P + (isE ? 1 : 4);
                const float* iga = P + (isE ? 23 : 26);
                const float* c0 = P + (isE ? 13 : 16);
                const float* cc = P + (isE ? 7 : 10);
                float kbrec = isE ? P[19] : P[21];
                float kbrel = isE ? P[20] : P[22];
                int aofs = (isE ? 0 : AI_OFF) + 3 * na;
                int bofs = isE ? (BE_OFF + n) : (BI_OFF + na);
#pragma unroll
                for (int q = 0; q < 4; ++q) {
                    int m = m0 + q;
                    float* row = stateOut + (size_t)m * SS;
                    int idx = m * N_TOT + n;
                    float Isyn = acc[i][j][q] + Iext[idx];
                    float x = row[X_OFF + n];
                    float xn = (x + gx * Isyn) * inv1gx;
                    row[X_OFF + n] = xn;

                    float r = r_ws[idx];
                    float* a = row + aofs;
                    float av0 = (a[0] + ga[0] * (r + c0[0])) * iga[0];
                    float av1 = (a[1] + ga[1] * (r + c0[1])) * iga[1];
                    float av2 = (a[2] + ga[2] * (r + c0[2])) * iga[2];
                    a[0] = av0; a[1] = av1; a[2] = av2;

                    float bb = row[bofs];
                    bb = (bb + kbrec) / (1.f + kbrec + kbrel * r);
                    row[bofs] = bb;

                    if (CALC_R) {
                        float xeff = xn - (av0 * cc[0] + av1 * cc[1] + av2 * cc[2]);
                        float rn = psig(xeff);
                        r_ws[idx] = rn;
                        rdep_out[idx] = f2bf(bb * rn);
                    }
                }
            }
        }
    }
}

// ---------- launch ----------
extern "C" void kernel_launch(void* const* d_in, const int* in_sizes, int n_in,
                              void* d_out, int out_size, void* d_ws, size_t ws_size,
                              hipStream_t stream) {
    const float* W_raw = (const float*)d_in[0];
    const float* W_in  = (const float*)d_in[1];
    const float* mask  = (const float*)d_in[2];
    const float* a_0   = (const float*)d_in[3];
    const float* ltd   = (const float*)d_in[4];
    const float* loE   = (const float*)d_in[5];
    const float* hiE   = (const float*)d_in[6];
    const float* lcE   = (const float*)d_in[7];
    const float* c0E   = (const float*)d_in[8];
    const float* loI   = (const float*)d_in[9];
    const float* hiI   = (const float*)d_in[10];
    const float* lcI   = (const float*)d_in[11];
    const float* c0I   = (const float*)d_in[12];
    const float* recE  = (const float*)d_in[13];
    const float* relE  = (const float*)d_in[14];
    const float* recI  = (const float*)d_in[15];
    const float* relI  = (const float*)d_in[16];
    const float* u     = (const float*)d_in[17];
    const float* state = (const float*)d_in[18];
    float* out = (float*)d_out;
    char* wsb = (char*)d_ws;

    ushort* We     = (ushort*)(wsb);                 // 8 MB
    float*  Iext   = (float*)(wsb + (8u << 20));     // 4 MB
    float*  r_ws   = (float*)(wsb + (12u << 20));    // 4 MB
    ushort* rdep0  = (ushort*)(wsb + (16u << 20));   // 2 MB
    ushort* rdep1  = (ushort*)(wsb + (18u << 20));   // 2 MB
    ushort* u_bf   = (ushort*)(wsb + (20u << 20));   // 0.5 MB
    ushort* win_bf = (ushort*)(wsb + (21u << 20));   // 2 MB
    float*  P      = (float*)(wsb + (23u << 20));    // 128 B

    hipMemcpyAsync(out, state, (size_t)BATCH * SS * sizeof(float),
                   hipMemcpyDeviceToDevice, stream);

    k_params<<<1, 64, 0, stream>>>(ltd, loE, hiE, lcE, c0E, loI, hiI, lcI, c0I,
                                   recE, relE, recI, relI, P);

    k_weff<<<(N_TOT * N_TOT / 4) / 256, 256, 0, stream>>>(W_raw, mask, We);
    k_cvt<<<(BATCH * IN_SZ / 4) / 256, 256, 0, stream>>>(u, u_bf);
    k_cvt<<<(N_TOT * IN_SZ / 4) / 256, 256, 0, stream>>>(W_in, win_bf);

    // I_ext = u @ W_in^T + a_0   (MFMA, K=512)
    mgemm<0, false><<<dim3(N_TOT / 64, BATCH / 64), 256, 0, stream>>>(
        u_bf, win_bf, IN_SZ, a_0, nullptr, Iext, nullptr, nullptr, nullptr, nullptr);

    k_r_first<<<(BATCH * N_TOT) / 256, 256, 0, stream>>>(out, P, r_ws, rdep0);

    ushort* rbufs[2] = {rdep0, rdep1};
    for (int t = 0; t < 6; ++t) {
        ushort* rin  = rbufs[t & 1];
        ushort* rout = rbufs[(t + 1) & 1];
        if (t < 5)
            mgemm<1, true><<<dim3(N_TOT / 64, BATCH / 64), 256, 0, stream>>>(
                rin, We, N_TOT, nullptr, Iext, nullptr, out, P, r_ws, rout);
        else
            mgemm<1, false><<<dim3(N_TOT / 64, BATCH / 64), 256, 0, stream>>>(
                rin, We, N_TOT, nullptr, Iext, nullptr, out, P, r_ws, nullptr);
    }
}